// Round 1
// baseline (787.738 us; speedup 1.0000x reference)
//
#include <hip/hip_runtime.h>
#include <hip/hip_bf16.h>

#define B_ 64
#define S_ 720
#define C_ 321
#define P_ 336
#define SP 736          // S padded to multiple of 32 (zeros)
#define WIN 25
#define PADW 12
#define NTILE 112       // P per block (3 blocks/channel)
#define KSTEPS 23       // 736/32

typedef __bf16 bf16x8 __attribute__((ext_vector_type(8)));
typedef float f32x4 __attribute__((ext_vector_type(4)));

__device__ __forceinline__ unsigned short f2bf(float f) {
  unsigned int u = __builtin_bit_cast(unsigned int, f);
  u += 0x7FFFu + ((u >> 16) & 1u);   // RNE
  return (unsigned short)(u >> 16);
}

// Pass 0: x[B,S,C] -> resT[C][B][SP] bf16, seasonT[C][B][SP] bf16 (zero-padded K tail)
__global__ __launch_bounds__(256) void pass0_decomp(
    const float* __restrict__ x,
    ushort2* __restrict__ resT,
    ushort2* __restrict__ seaT) {
  __shared__ float xpad[S_ + 2 * PADW];   // 744 floats, zero halo both ends
  int blk = blockIdx.x;                   // b*C_ + c  (consecutive blocks share x cache lines)
  int b = blk / C_;
  int c = blk - b * C_;
  int t = threadIdx.x;
  for (int s = t; s < S_; s += 256) xpad[PADW + s] = x[(b * S_ + s) * C_ + c];
  if (t < PADW) { xpad[t] = 0.f; xpad[PADW + S_ + t] = 0.f; }
  __syncthreads();
  int rowbase = (c * B_ + b) * (SP / 2);
  for (int p = t; p < SP / 2; p += 256) {
    if (p < S_ / 2) {
      int s0 = 2 * p;
      float w0 = 0.f;
#pragma unroll
      for (int j = 0; j < WIN; ++j) w0 += xpad[s0 + j];
      float w1 = w0 - xpad[s0] + xpad[s0 + WIN];
      float sea0 = w0 * (1.0f / WIN), sea1 = w1 * (1.0f / WIN);
      float x0 = xpad[PADW + s0], x1 = xpad[PADW + s0 + 1];
      resT[rowbase + p] = make_ushort2(f2bf(x0 - sea0), f2bf(x1 - sea1));
      seaT[rowbase + p] = make_ushort2(f2bf(sea0), f2bf(sea1));
    } else {
      resT[rowbase + p] = make_ushort2(0, 0);
      seaT[rowbase + p] = make_ushort2(0, 0);
    }
  }
}

// GEMM: per block = (channel c, p-tile of 112). 4 waves, each owns one 16-row m-tile.
// acc[b,p] += res·W_res + season·W_trend (single accumulator, two MFMA chains).
__global__ __launch_bounds__(256) void gemm_fused(
    const uint4* __restrict__ abase,   // resT; seaT at +1890048 uint4
    const float4* __restrict__ wR,
    const float4* __restrict__ wT,
    const float* __restrict__ bR,
    const float* __restrict__ bT,
    float* __restrict__ out) {
  __shared__ __align__(16) unsigned char lds[8192 + 14336 + 448];
  unsigned char* ldsA = lds;                       // [2][64][32] bf16
  unsigned char* ldsB = lds + 8192;                // [2][112][32] bf16
  float* bsum = (float*)(lds + 8192 + 14336);      // 112 floats

  int blk = blockIdx.x;
  int c = blk / 3;
  int nt = blk - c * 3;
  int p0 = nt * NTILE;
  int t = threadIdx.x;
  int w = t >> 6;
  int lane = t & 63;
  int col = lane & 15;
  int quad = lane >> 4;

  if (t < NTILE) bsum[t] = bR[c * P_ + p0 + t] + bT[c * P_ + p0 + t];

  // A staging: 512 x 16B chunks total, 2 per thread
  int aOffG[2], aOffL[2];
#pragma unroll
  for (int i = 0; i < 2; ++i) {
    int idx = i * 256 + t;
    int m = idx >> 8;             // 0=res, 1=season (wave-uniform)
    int r = (idx >> 2) & 63;      // row (batch)
    int k16 = idx & 3;            // 16B chunk within 32-k row
    aOffG[i] = m * 1890048 + c * 5888 + r * 92 + k16;   // uint4 units
    aOffL[i] = m * 4096 + r * 64 + k16 * 16;            // bytes
  }
  // B staging: 1792 float4 chunks (fp32), 7 per thread -> bf16 LDS
  int bOffG[7], bOffL[7], bK4[7], bM[7];
#pragma unroll
  for (int i = 0; i < 7; ++i) {
    int idx = i * 256 + t;
    int m = idx / 896;            // wave-uniform split
    int rem = idx - m * 896;
    int r = rem >> 3;             // p row 0..111
    int k4 = rem & 7;             // float4 within 32-k row
    bM[i] = m;
    bK4[i] = k4;
    bOffG[i] = c * 60480 + (p0 + r) * 180 + k4;         // float4 units
    bOffL[i] = m * 7168 + r * 64 + k4 * 8;              // bytes
  }

  f32x4 acc[7];
#pragma unroll
  for (int i = 0; i < 7; ++i) acc[i] = (f32x4){0.f, 0.f, 0.f, 0.f};

  int aFragOff = (w * 16 + col) * 64 + quad * 16;

  for (int ks = 0; ks < KSTEPS; ++ks) {
    uint4 av[2];
#pragma unroll
    for (int i = 0; i < 2; ++i) av[i] = abase[aOffG[i] + ks * 4];
    float4 bv[7];
#pragma unroll
    for (int i = 0; i < 7; ++i) {
      float4 v = {0.f, 0.f, 0.f, 0.f};
      if (ks * 32 + bK4[i] * 4 < S_) {                  // zero-pad K tail (720..735)
        const float4* src = bM[i] ? wT : wR;
        v = src[bOffG[i] + ks * 8];
      }
      bv[i] = v;
    }
    __syncthreads();   // prev iter's frag reads done (also orders bsum on ks=0)
#pragma unroll
    for (int i = 0; i < 2; ++i) *(uint4*)(ldsA + aOffL[i]) = av[i];
#pragma unroll
    for (int i = 0; i < 7; ++i) {
      ushort4 pk;
      pk.x = f2bf(bv[i].x); pk.y = f2bf(bv[i].y);
      pk.z = f2bf(bv[i].z); pk.w = f2bf(bv[i].w);
      *(ushort4*)(ldsB + bOffL[i]) = pk;
    }
    __syncthreads();
    bf16x8 aR = *(const bf16x8*)(ldsA + aFragOff);
    bf16x8 aS = *(const bf16x8*)(ldsA + 4096 + aFragOff);
#pragma unroll
    for (int tt = 0; tt < 7; ++tt) {
      int bo = (tt * 16 + col) * 64 + quad * 16;
      bf16x8 bRf = *(const bf16x8*)(ldsB + bo);
      bf16x8 bTf = *(const bf16x8*)(ldsB + 7168 + bo);
      acc[tt] = __builtin_amdgcn_mfma_f32_16x16x32_bf16(aR, bRf, acc[tt], 0, 0, 0);
      acc[tt] = __builtin_amdgcn_mfma_f32_16x16x32_bf16(aS, bTf, acc[tt], 0, 0, 0);
    }
  }

  // Epilogue: C/D map col=lane&15 (p), row=quad*4+reg (b)
#pragma unroll
  for (int tt = 0; tt < 7; ++tt) {
    int p = p0 + tt * 16 + col;
    float bs = bsum[tt * 16 + col];
#pragma unroll
    for (int r = 0; r < 4; ++r) {
      int brow = w * 16 + quad * 4 + r;
      out[(brow * C_ + c) * P_ + p] = acc[tt][r] + bs;
    }
  }
}

extern "C" void kernel_launch(void* const* d_in, const int* in_sizes, int n_in,
                              void* d_out, int out_size, void* d_ws, size_t ws_size,
                              hipStream_t stream) {
  const float* x = (const float*)d_in[0];
  const float4* wR = (const float4*)d_in[1];
  const float* bR = (const float*)d_in[2];
  const float4* wT = (const float4*)d_in[3];
  const float* bT = (const float*)d_in[4];
  float* out = (float*)d_out;

  ushort2* resT = (ushort2*)d_ws;                               // [C][B][SP/2]
  ushort2* seaT = resT + (size_t)C_ * B_ * (SP / 2);            // +30,240,768 B

  pass0_decomp<<<B_ * C_, 256, 0, stream>>>(x, resT, seaT);
  gemm_fused<<<C_ * 3, 256, 0, stream>>>((const uint4*)d_ws, wR, wT, bR, bT, out);
}

// Round 2
// 748.648 us; speedup vs baseline: 1.0522x; 1.0522x over previous
//
#include <hip/hip_runtime.h>
#include <hip/hip_bf16.h>

#define B_ 64
#define S_ 720
#define C_ 321
#define P_ 336
#define SP 736          // S padded to multiple of 32 (zeros)
#define WIN 25
#define PADW 12
#define NTILE 112       // P per block (3 blocks/channel)
#define KSTEPS 23       // 736/32
#define CT 8            // channels per pass0 block
#define AQ_PER_MAT 1890048   // uint4 per matrix: 321*64*92

typedef __bf16 bf16x8 __attribute__((ext_vector_type(8)));
typedef float f32x4 __attribute__((ext_vector_type(4)));

__device__ __forceinline__ unsigned short f2bf(float f) {
  unsigned int u = __builtin_bit_cast(unsigned int, f);
  u += 0x7FFFu + ((u >> 16) & 1u);   // RNE
  return (unsigned short)(u >> 16);
}

// Pass 0 (coalesced): block = (ctile, b). Loads x[b, :, c0:c0+8] with 32B
// row segments, LDS-transposes, sliding-window avgpool per channel, writes
// resT/seaT rows [C][B][SP] as contiguous 1472B runs.
__global__ __launch_bounds__(256) void pass0_decomp(
    const float* __restrict__ x,
    uint4* __restrict__ resQ,
    uint4* __restrict__ seaQ) {
  __shared__ float xs[CT][745];                   // [c][PADW + s], +1 pad (745%32=9)
  __shared__ unsigned short obuf[2 * CT * SP];    // [m][c][s] bf16
  int c0 = blockIdx.x * CT;
  int b = blockIdx.y;
  int t = threadIdx.x;

  // halos: zero xs[:, 0:12) and [732:744); zero obuf K-tail s in [720,736)
  if (t < CT * 24) {
    int c = t / 24, h = t % 24;
    xs[c][h < 12 ? h : h + 720] = 0.f;
  }
  {
    int m = t >> 7, c = (t >> 4) & 7, s = 720 + (t & 15);
    obuf[(m * CT + c) * SP + s] = 0;
  }
  // load: lane c fastest (consecutive addresses within a row segment)
  {
    int c = t & 7;
    int svalid = (c0 + c < C_);
    for (int p = 0; p < 23; ++p) {
      int s = (t >> 3) + p * 32;
      if (s < S_ && svalid) xs[c][PADW + s] = x[(b * S_ + s) * C_ + c0 + c];
    }
  }
  __syncthreads();
  // sliding window: thread = (c, chunk of 23 outputs)
  {
    int c = t & 7;
    int s0 = (t >> 3) * 23;
    int s1 = s0 + 23; if (s1 > S_) s1 = S_;
    float wsum = 0.f;
#pragma unroll
    for (int j = 0; j < WIN; ++j) wsum += xs[c][s0 + j];
    for (int s = s0; s < s1; ++s) {
      float sea = wsum * (1.0f / WIN);
      float res = xs[c][s + PADW] - sea;
      obuf[c * SP + s] = f2bf(res);
      obuf[(CT + c) * SP + s] = f2bf(sea);
      wsum += xs[c][s + WIN] - xs[c][s];
    }
  }
  __syncthreads();
  // writeout: 16 rows (2m x 8c) x 92 uint4, fully coalesced
  const uint4* ob = (const uint4*)obuf;
  for (int i = t; i < 2 * CT * 92; i += 256) {
    int row = i / 92;
    int off = i - row * 92;
    int c = row & 7;
    int m = row >> 3;
    if (c0 + c < C_) {
      uint4* dst = m ? seaQ : resQ;
      dst[((c0 + c) * B_ + b) * 92 + off] = ob[row * 92 + off];
    }
  }
}

// GEMM: block = (channel c, 112-wide p-tile). Software-pipelined: global
// loads for iter ks+1 issued after the LDS-ready barrier, overlapping the
// ds_read+MFMA phase of iter ks. LDS rows padded to 80B (2-way banks = free).
__global__ __launch_bounds__(256) void gemm_fused(
    const uint4* __restrict__ abase,   // resT; seaT at +AQ_PER_MAT uint4
    const float4* __restrict__ wR,
    const float4* __restrict__ wT,
    const float* __restrict__ bR,
    const float* __restrict__ bT,
    float* __restrict__ out) {
  __shared__ __align__(16) unsigned char lds[10240 + 17920 + 448];
  unsigned char* ldsA = lds;                       // [2][64 rows][80B] (32 bf16 + pad)
  unsigned char* ldsB = lds + 10240;               // [2][112 rows][80B]
  float* bsum = (float*)(lds + 10240 + 17920);     // 112 floats

  int blk = blockIdx.x;
  int c = blk / 3;
  int nt = blk - c * 3;
  int p0 = nt * NTILE;
  int t = threadIdx.x;
  int w = t >> 6;
  int lane = t & 63;
  int col = lane & 15;
  int quad = lane >> 4;

  if (t < NTILE) bsum[t] = bR[c * P_ + p0 + t] + bT[c * P_ + p0 + t];

  // A staging: 512 x 16B chunks, 2 per thread
  int aOffG[2], aOffL[2];
#pragma unroll
  for (int i = 0; i < 2; ++i) {
    int idx = i * 256 + t;
    int m = idx >> 8;             // 0=res, 1=season (wave-uniform)
    int r = (idx >> 2) & 63;      // batch row
    int k16 = idx & 3;            // 16B chunk within 32-k row
    aOffG[i] = m * AQ_PER_MAT + c * 5888 + r * 92 + k16;   // uint4 units
    aOffL[i] = m * 5120 + r * 80 + k16 * 16;               // bytes
  }
  // B staging: 1792 float4 (fp32) chunks, 7 per thread -> bf16 LDS
  int bOffG[7], bOffL[7], bK4[7], bM[7];
#pragma unroll
  for (int i = 0; i < 7; ++i) {
    int idx = i * 256 + t;
    int m = idx / 896;
    int rem = idx - m * 896;
    int r = rem >> 3;             // p row 0..111
    int k4 = rem & 7;             // float4 within 32-k row
    bM[i] = m;
    bK4[i] = k4;
    bOffG[i] = c * 60480 + (p0 + r) * 180 + k4;            // float4 units
    bOffL[i] = m * 8960 + r * 80 + k4 * 8;                 // bytes
  }

  f32x4 acc[7];
#pragma unroll
  for (int i = 0; i < 7; ++i) acc[i] = (f32x4){0.f, 0.f, 0.f, 0.f};

  int aFragOff = (w * 16 + col) * 80 + quad * 16;

  // ---- prologue: load iter 0 into registers ----
  uint4 av[2];
  float4 bv[7];
#pragma unroll
  for (int i = 0; i < 2; ++i) av[i] = abase[aOffG[i]];
#pragma unroll
  for (int i = 0; i < 7; ++i) {
    float4 v = {0.f, 0.f, 0.f, 0.f};
    if (bK4[i] * 4 < S_) {
      const float4* src = bM[i] ? wT : wR;
      v = src[bOffG[i]];
    }
    bv[i] = v;
  }

  for (int ks = 0; ks < KSTEPS; ++ks) {
    __syncthreads();   // prev iter's frag reads done (also orders bsum on ks=0)
#pragma unroll
    for (int i = 0; i < 2; ++i) *(uint4*)(ldsA + aOffL[i]) = av[i];
#pragma unroll
    for (int i = 0; i < 7; ++i) {
      ushort4 pk;
      pk.x = f2bf(bv[i].x); pk.y = f2bf(bv[i].y);
      pk.z = f2bf(bv[i].z); pk.w = f2bf(bv[i].w);
      *(ushort4*)(ldsB + bOffL[i]) = pk;
    }
    __syncthreads();
    // ---- prefetch iter ks+1 (latency overlaps MFMA below) ----
    if (ks + 1 < KSTEPS) {
      int kn = ks + 1;
#pragma unroll
      for (int i = 0; i < 2; ++i) av[i] = abase[aOffG[i] + kn * 4];
#pragma unroll
      for (int i = 0; i < 7; ++i) {
        float4 v = {0.f, 0.f, 0.f, 0.f};
        if (kn * 32 + bK4[i] * 4 < S_) {
          const float4* src = bM[i] ? wT : wR;
          v = src[bOffG[i] + kn * 8];
        }
        bv[i] = v;
      }
    }
    // ---- compute on current LDS tile ----
    bf16x8 aR = *(const bf16x8*)(ldsA + aFragOff);
    bf16x8 aS = *(const bf16x8*)(ldsA + 5120 + aFragOff);
#pragma unroll
    for (int tt = 0; tt < 7; ++tt) {
      int bo = (tt * 16 + col) * 80 + quad * 16;
      bf16x8 bRf = *(const bf16x8*)(ldsB + bo);
      bf16x8 bTf = *(const bf16x8*)(ldsB + 8960 + bo);
      acc[tt] = __builtin_amdgcn_mfma_f32_16x16x32_bf16(aR, bRf, acc[tt], 0, 0, 0);
      acc[tt] = __builtin_amdgcn_mfma_f32_16x16x32_bf16(aS, bTf, acc[tt], 0, 0, 0);
    }
  }

  // Epilogue: C/D map col=lane&15 (p), row=quad*4+reg (b). r outer, tt inner
  // so each (brow) emits 7 ascending 64B segments (448B run) for L2 merge.
#pragma unroll
  for (int r = 0; r < 4; ++r) {
    int brow = w * 16 + quad * 4 + r;
#pragma unroll
    for (int tt = 0; tt < 7; ++tt) {
      int p = p0 + tt * 16 + col;
      out[(brow * C_ + c) * P_ + p] = acc[tt][r] + bsum[tt * 16 + col];
    }
  }
}

extern "C" void kernel_launch(void* const* d_in, const int* in_sizes, int n_in,
                              void* d_out, int out_size, void* d_ws, size_t ws_size,
                              hipStream_t stream) {
  const float* x = (const float*)d_in[0];
  const float4* wR = (const float4*)d_in[1];
  const float* bR = (const float*)d_in[2];
  const float4* wT = (const float4*)d_in[3];
  const float* bT = (const float*)d_in[4];
  float* out = (float*)d_out;

  uint4* resQ = (uint4*)d_ws;                    // [C][B][92] uint4 (bf16 rows)
  uint4* seaQ = resQ + AQ_PER_MAT;

  dim3 g0((C_ + CT - 1) / CT, B_);               // 41 x 64
  pass0_decomp<<<g0, 256, 0, stream>>>(x, resQ, seaQ);
  gemm_fused<<<C_ * 3, 256, 0, stream>>>((const uint4*)d_ws, wR, wT, bR, bT, out);
}